// Round 1
// 98.709 us; speedup vs baseline: 1.0288x; 1.0288x over previous
//
#include <hip/hip_runtime.h>
#include <math.h>
#include <stdint.h>

// SemiConv2d tropical conv: out = max_{ic,kh,kw} min(x_pad, K). f16-packed.
// R14: ROW-GRANULAR early-exit table. Theory: R13 main (~40us) exceeds its
// VALU-issue ceiling at zero-exit (19us) but matches the L2-byte roofline
// at ~half the taps (2.7GB full-scan -> 77us; measured 40us) => kernel is
// L2-BW-bound and true coherent exit is ~140-150 taps, not 40-48. Lever is
// bytes/tap: one dwordx2 at a row base already holds ALL THREE kw taps of
// an (ic,dh) row: kw0=q.x, kw1=alignbit(q.y,q.x,16), kw2=q.y. Table is now
// 96 row-entries/oc {k0dup,k1dup,k2dup,off}, sorted desc by rowmax, plus a
// parallel rmax-dup table for the exit threshold. Exact: rmx[next] bounds
// every remaining tap (sort monotone, f16 cvt monotone); first R rows are
// a superset of the top-R taps, so exit fires no later than R13. Expected
// loads/thread ~150 -> ~80 (x0.55 L2 bytes); VALU/iter ~unchanged.
// Predict main 40 -> ~23us, total ~101.5 -> ~85us.
// R2-R13 evidence: structural variants pinned 38-53us => byte-conserving;
// only bytes/tap reduction left. Next levers if this lands: LDS staging
// (40KB/block, 245MB total L2) or 4-output threads on a non-redundant row
// layout (needs layout change; halves bytes/output again).

#define HH 96
#define WW 96
#define CIN 32
#define OCN 32
#define XQ_ROWS 98
#define XQ_W 48
#define XQ_SLICE (XQ_ROWS * XQ_W)              // uint2 units per (n,ic) slice
#define XQ_TOTAL (256 * XQ_SLICE)              // uint2 elements
#define NROW 96                                 // row-entries per oc
#define TBL_BYTES ((size_t)32 * NROW * 16)
#define RMX_BYTES ((size_t)32 * NROW * 4)
#define WS_NEED ((size_t)XQ_TOTAL * 8 + TBL_BYTES + RMX_BYTES)
#define NEGH2 0xFC00FC00u

typedef _Float16 h2 __attribute__((ext_vector_type(2)));
typedef uint32_t u2a4 __attribute__((ext_vector_type(2), aligned(4)));

__device__ __forceinline__ uint32_t pkmin_vs(uint32_t x, uint32_t k) {
    uint32_t d;
    asm("v_pk_min_f16 %0, %1, %2" : "=v"(d) : "v"(x), "s"(k));
    return d;
}
__device__ __forceinline__ uint32_t pkmin_vv(uint32_t a, uint32_t b) {
    uint32_t d;
    asm("v_pk_min_f16 %0, %1, %2" : "=v"(d) : "v"(a), "v"(b));
    return d;
}
__device__ __forceinline__ uint32_t pkmax(uint32_t a, uint32_t b) {
    uint32_t d;
    asm("v_pk_max_f16 %0, %1, %2" : "=v"(d) : "v"(a), "v"(b));
    return d;
}
__device__ __forceinline__ uint32_t packh2(float lo, float hi) {
    h2 p = {(_Float16)lo, (_Float16)hi};
    return __builtin_bit_cast(uint32_t, p);
}

// xq[(s*98 + rowpad)*48 + j] = 4xf16 (x[2j-1],x[2j] | x[2j+1],x[2j+2]), s=n*32+ic
__global__ __launch_bounds__(256) void setup_xq(const float* __restrict__ x,
                                                uint2* __restrict__ xq) {
    int idx = blockIdx.x * 256 + threadIdx.x;   // over 256*98*48 = 1,204,224
    int j  = idx % XQ_W;
    int t  = idx / XQ_W;
    int hp = t % XQ_ROWS;
    int s  = t / XQ_ROWS;
    int h  = hp - 1;
    bool hv = (h >= 0) && (h < HH);
    const float* row = x + ((size_t)s * HH + (hv ? h : 0)) * WW;
    float a = (hv && j > 0)        ? row[2 * j - 1] : -INFINITY;
    float b = hv                   ? row[2 * j]     : -INFINITY;
    float c = hv                   ? row[2 * j + 1] : -INFINITY;
    float d = (hv && j < XQ_W - 1) ? row[2 * j + 2] : -INFINITY;
    uint2 v;
    v.x = packh2(a, b);
    v.y = packh2(c, d);
    xq[idx] = v;
}

// Per-oc ROW table sorted by rowmax descending.
// entry = {k_kw0 dup, k_kw1 dup, k_kw2 dup, byte_off of (ic,dh) row base}
// rmx[rank] = rowmax dup f16 (exit threshold: bounds all k of rows >= rank).
__global__ void setup_row(const float* __restrict__ kk, uint4* __restrict__ tbl,
                          uint32_t* __restrict__ rmx) {
    __shared__ float rs[NROW];
    const int oc = blockIdx.x;                  // 32 blocks
    const int t  = threadIdx.x;                 // 96 threads = ic*3 + dh
    const int ic = t / 3, dh = t - ic * 3;
    const float* kp = kk + ((size_t)(oc * CIN + ic) * 3 + dh) * 3;
    float k0 = kp[0], k1 = kp[1], k2 = kp[2];
    float rm = fmaxf(fmaxf(k0, k1), k2);
    rs[t] = rm;
    __syncthreads();
    int rank = 0;
    for (int s = 0; s < NROW; ++s) {
        float v = rs[s];
        rank += (v > rm) || (v == rm && s < t);
    }
    uint32_t off = (uint32_t)(ic * XQ_ROWS + dh) * (XQ_W * 8);
    tbl[oc * NROW + rank] = make_uint4(packh2(k0, k0), packh2(k1, k1),
                                       packh2(k2, k2), off);
    rmx[oc * NROW + rank] = packh2(rm, rm);
}

__global__ __launch_bounds__(192, 8) void semiconv_row(const char* __restrict__ xqb,
                                                       const uint4* __restrict__ tbl,
                                                       const uint32_t* __restrict__ rmx,
                                                       float* __restrict__ out) {
    const int tid = threadIdx.x;
    const int jj = tid % 48;          // w-pair 0..47
    const int hr = tid / 48;          // 0..3
    const int b  = blockIdx.x;
    const int hp = b % 24;            // hp FASTEST; XCD = hp%8 -> L2 locality
    const int t  = b / 24;
    const int oc = t & 31;
    const int n  = t >> 5;
    const int h  = hp * 4 + hr;       // one output row per thread (2 w)

    // base folds slice base + per-thread (h,jj) byte offset; entry off adds (ic,dh)
    const char* xb = xqb + (size_t)n * CIN * XQ_SLICE * 8
                         + (size_t)(h * XQ_W + jj) * 8;
    const uint4* tb = tbl + oc * NROW;
    const uint32_t* rb = rmx + oc * NROW;

    uint32_t acc = NEGH2;
    uint4 e0 = tb[0], e1 = tb[1];

    for (int c = 0; c < NROW / 2; ++c) {
        uint4 f0, f1; uint32_t fr;
        if (c < NROW / 2 - 1) {       // prefetch next row-pair (uniform -> s_load)
            const uint4* nb = tb + 2 * c + 2;
            f0 = nb[0]; f1 = nb[1];
            fr = rb[2 * c + 2];
        }
        // row e0: one 8B load covers all 3 kw taps
        u2a4 q0 = *(const u2a4*)(xb + e0.w);
        u2a4 q1 = *(const u2a4*)(xb + e1.w);
        uint32_t v01 = __builtin_amdgcn_alignbit(q0.y, q0.x, 16);
        uint32_t v11 = __builtin_amdgcn_alignbit(q1.y, q1.x, 16);
        uint32_t m0 = pkmax(pkmin_vs(q0.x, e0.x), pkmin_vs(v01, e0.y));
        m0 = pkmax(m0, pkmin_vs(q0.y, e0.z));
        uint32_t m1 = pkmax(pkmin_vs(q1.x, e1.x), pkmin_vs(v11, e1.y));
        m1 = pkmax(m1, pkmin_vs(q1.y, e1.z));
        acc = pkmax(acc, pkmax(m0, m1));

        if (c < NROW / 2 - 1) {
            // done iff min(acc.lo, acc.hi) >= next rowmax (max of all remaining)
            uint32_t sw = __builtin_amdgcn_alignbit(acc, acc, 16);
            uint32_t mn = pkmin_vv(acc, sw);
            h2 a  = __builtin_bit_cast(h2, mn);
            h2 kn = __builtin_bit_cast(h2, fr);
            if (__all((float)a.x >= (float)kn.x)) break;
            e0 = f0; e1 = f1;
        }
    }

    h2 a = __builtin_bit_cast(h2, acc);
    float2 v = make_float2((float)a.x, (float)a.y);
    *(float2*)(out + (((size_t)(n * OCN + oc)) * HH + h) * WW + 2 * jj) = v;
}

// ---------- f32 fallback if ws is too small ----------
#define NEGINF (-INFINITY)
__global__ __launch_bounds__(192, 8) void semiconv2d_f32(
    const float* __restrict__ x, const float* __restrict__ kk, float* __restrict__ out)
{
    const int tid = threadIdx.x;
    const int w  = tid % WW;
    const int hr = tid / WW;
    const int b   = blockIdx.x;
    const int ocb = b & 7;
    const int hp  = (b >> 3) % 48;
    const int n   = (b >> 3) / 48;
    const int h   = hp * 2 + hr;
    const int oc0 = ocb * 4;
    float a0[4], a1[4], a2[4];
#pragma unroll
    for (int i = 0; i < 4; ++i) { a0[i] = NEGINF; a1[i] = NEGINF; a2[i] = NEGINF; }
    const bool vm = (h > 0), vp = (h < HH - 1);
    const int hm  = vm ? h - 1 : h;
    const int hpl = vp ? h + 1 : h;
    const int cm  = (w > 0) ? -1 : 0;
    const int cp  = (w < WW - 1) ? 1 : 0;
    const float* rm = x + ((size_t)(n * CIN) * HH + hm)  * WW + w;
    const float* r1 = x + ((size_t)(n * CIN) * HH + h)   * WW + w;
    const float* rp = x + ((size_t)(n * CIN) * HH + hpl) * WW + w;
#pragma unroll 2
    for (int ic = 0; ic < CIN; ++ic) {
        float r00 = vm ? rm[cm] : NEGINF, r01 = vm ? rm[0] : NEGINF, r02 = vm ? rm[cp] : NEGINF;
        float r10 = r1[cm], r11 = r1[0], r12 = r1[cp];
        float r20 = vp ? rp[cm] : NEGINF, r21 = vp ? rp[0] : NEGINF, r22 = vp ? rp[cp] : NEGINF;
#pragma unroll
        for (int oc = 0; oc < 4; ++oc) {
            const float* kq = kk + (size_t)(((oc0 + oc) * CIN + ic)) * 9;
            a0[oc] = fmaxf(fmaxf(a0[oc], fminf(r00, kq[0])), fmaxf(fminf(r10, kq[3]), fminf(r20, kq[6])));
            a1[oc] = fmaxf(fmaxf(a1[oc], fminf(r01, kq[1])), fmaxf(fminf(r11, kq[4]), fminf(r21, kq[7])));
            a2[oc] = fmaxf(fmaxf(a2[oc], fminf(r02, kq[2])), fmaxf(fminf(r12, kq[5]), fminf(r22, kq[8])));
        }
        rm += HH * WW; r1 += HH * WW; rp += HH * WW;
    }
#pragma unroll
    for (int oc = 0; oc < 4; ++oc) {
        float v0 = (w > 0)      ? a0[oc] : NEGINF;
        float v2 = (w < WW - 1) ? a2[oc] : NEGINF;
        out[(((size_t)(n * OCN + oc0 + oc)) * HH + h) * WW + w] = fmaxf(fmaxf(v0, a1[oc]), v2);
    }
}

extern "C" void kernel_launch(void* const* d_in, const int* in_sizes, int n_in,
                              void* d_out, int out_size, void* d_ws, size_t ws_size,
                              hipStream_t stream) {
    const float* x  = (const float*)d_in[0];
    const float* kk = (const float*)d_in[1];
    float* out      = (float*)d_out;
    if (ws_size >= WS_NEED) {
        uint2*    xq  = (uint2*)d_ws;
        uint4*    tbl = (uint4*)((char*)d_ws + (size_t)XQ_TOTAL * 8);
        uint32_t* rmx = (uint32_t*)((char*)d_ws + (size_t)XQ_TOTAL * 8 + TBL_BYTES);
        setup_xq<<<dim3(XQ_TOTAL / 256), dim3(256), 0, stream>>>(x, xq);
        setup_row<<<dim3(32), dim3(NROW), 0, stream>>>(kk, tbl, rmx);
        semiconv_row<<<dim3(8 * 32 * 24), dim3(192), 0, stream>>>(
            (const char*)xq, tbl, rmx, out);
    } else {
        semiconv2d_f32<<<dim3(8 * 48 * 8), dim3(192), 0, stream>>>(x, kk, out);
    }
}